// Round 2
// baseline (244.938 us; speedup 1.0000x reference)
//
#include <hip/hip_runtime.h>

// Problem constants (from reference): B,R,C,H,W = 4,2,19,256,512
constexpr int B = 4, R = 2, C = 19, H = 256, W = 512;
constexpr int HW = H * W;

// Output tile per block: 64 x 16 px; 256 threads.
// Thread (tx,ty) owns 4 px STRIDED by 16: x = x0 + tx + 16*p. This makes
// each gather instruction's lane columns 16-consecutive per ty-group; with
// TW % 32 == 24 the four ty-groups land at bank shifts {0,24,16,8} -> exact
// uniform 2-way LDS banking (free, cf. m136). Consecutive-px mapping was a
// structural 8-way conflict (5.9M conflict cycles measured in R1).
constexpr int BX = 64, BY = 16;
constexpr int NBX = W / BX;              // 8
constexpr int NBY = H / BY;              // 16
constexpr int NSPAT = B * NBX * NBY;     // 512 spatial tiles
constexpr int NCHUNK = 4;                // channel chunks -> 2048 blocks = 8/CU work

// Pred tile staged in LDS per (channel, ref): halo 10 px (5 sigma of mv/4).
constexpr int TW = 88;                   // 64 + 12 left + 12 right slack, TW%32==24
constexpr int TH = 37;                   // 16 + 10 up + 11 down
constexpr int TILE_N = TW * TH;          // 3256 floats = 13.02 KB (x2 = 26.05 KB/block)
constexpr int TILE_V4 = TILE_N / 4;      // 814 float4s (TW/4 = 22 per row)
// Tile rows pack contiguously (TW = 22*4): phys float index of the idx-th
// float4 is idx*4 -> staging is exactly the wave-linear layout
// global_load_lds needs (uniform LDS base + lane*16B, per-lane GLOBAL src).

// Direct global->LDS DMA, 16B per lane. No VGPR round-trip (cf. the R5/R6
// lesson: register staging buffers spilled to scratch and were 2.4x slower).
#define GLD_LDS16(gsrc, ldst)                                                  \
    __builtin_amdgcn_global_load_lds(                                          \
        (const __attribute__((address_space(1))) void*)(gsrc),                 \
        (__attribute__((address_space(3))) void*)(ldst), 16, 0, 0)

// R4 tap-math body (proven: VGPR 64, zero spill) + 4-way channel chunking
// and 26 KB tiles -> 6 blocks/CU (launch_bounds 256,6; VGPR budget 84).
// DO NOT add register prefetch buffers here: R5/R6 showed the compiler
// pushes them (and tap state) to scratch -> 280+ MB WRITE_SIZE, 2.4x slower.
__global__ __launch_bounds__(256, 6) void mc_warp_kernel(
    const float* __restrict__ pred,   // [B,R,C,H,W]
    const float* __restrict__ mv,     // [B,R,2,H,W] quarter-pel
    const float* __restrict__ wgt,    // [B,R,1,H,W]
    float* __restrict__ out)          // [B,C,H,W]
{
    __shared__ float tile0[TILE_N];
    __shared__ float tile1[TILE_N];

    int t = threadIdx.x;
    // XCD band swizzle on the spatial index: each XCD owns a contiguous
    // (b, y-band); all channel-chunks of a tile land on the same XCD
    // (gridDim.x = 512 is a multiple of 8) -> mv/wgt L2 reuse across chunks.
    int xcd  = blockIdx.x & 7;
    int slot = blockIdx.x >> 3;
    int vblk = xcd * (NSPAT / 8) + slot;
    int bx   = vblk & (NBX - 1);
    int by   = (vblk >> 3) & (NBY - 1);
    int b    = vblk >> 7;
    int x0 = bx * BX, y0 = by * BY;
    int tx = t & 15, ty = t >> 4;
    int y  = y0 + ty;
    int xb = x0 + tx;                     // px p of this thread = xb + 16*p

    // Tile origin, clamped fully inside the image (staging needs no clamps).
    // colbase stays float4-aligned (x0 mult of 64, W-TW = 424 mult of 4).
    int rowbase = min(max(y0 - 10, 0), H - TH);
    int colbase = min(max(x0 - 12, 0), W - TW);

    const float* pl0 = pred + (size_t)(b * R + 0) * C * HW;
    const float* pl1 = pred + (size_t)(b * R + 1) * C * HW;
    const float* st0 = pl0 + (size_t)rowbase * W + colbase;
    const float* st1 = pl1 + (size_t)rowbase * W + colbase;

    int cbeg = (C * blockIdx.y) / NCHUNK;        // {0,4,9,14}
    int cend = (C * (blockIdx.y + 1)) / NCHUNK;  // {4,9,14,19}

    // Issue the FIRST channel's staging now (direct global->LDS DMA); it
    // overlaps with the ~300-op tap-setup math below. Unconditional: if the
    // block later takes the fallback path the staged data is simply unused.
    {
        const float* s0 = st0 + (size_t)cbeg * HW;
        const float* s1 = st1 + (size_t)cbeg * HW;
        #pragma unroll
        for (int i = 0; i < 4; ++i) {
            int idx = t + i * 256;
            if (idx < TILE_V4) {
                int row = idx / 22;               // 22 float4s per tile row
                int off = idx * 4 + row * (W - TW);   // == row*W + c4
                GLD_LDS16(s0 + off, &tile0[idx * 4]);
                GLD_LDS16(s1 + off, &tile1[idx * 4]);
            }
        }
    }

    // Per-(ref, px) tap state: two row-pair offsets + 4 pair weights.
    int   off0[R][4], off1[R][4];
    int   offL0[R][4], offL1[R][4], offG0[R][4], offG1[R][4];
    float wq[R][4][4];
    int flag = 0;

    #pragma unroll
    for (int r = 0; r < R; ++r) {
        const float* mvxp = mv + (size_t)((b * R + r) * 2) * HW + (size_t)y * W + xb;
        const float* mvyp = mvxp + HW;
        const float* wp   = wgt + (size_t)(b * R + r) * HW + (size_t)y * W + xb;
        float mxs[4], mys[4], wrs[4];
        #pragma unroll
        for (int p = 0; p < 4; ++p) {     // imm-offset scalar loads, 64B-coalesced
            mxs[p] = mvxp[16 * p];
            mys[p] = mvyp[16 * p];
            wrs[p] = wp[16 * p];
        }
        #pragma unroll
        for (int p = 0; p < 4; ++p) {
            int x = xb + 16 * p;
            float gx = (float)x + mxs[p] * 0.25f;   // quarter-pel -> pixel
            float gy = (float)y + mys[p] * 0.25f;
            float fx0 = floorf(gx), fy0 = floorf(gy);
            float wx1 = gx - fx0, wx0 = 1.0f - wx1;
            float wy1 = gy - fy0, wy0 = 1.0f - wy1;
            int ix0 = (int)fx0, iy0 = (int)fy0;
            int ix1 = ix0 + 1,  iy1 = iy0 + 1;

            // x pair: shift base into [0, W-2], route wx0/wx1 per element.
            int base = min(max(ix0, 0), W - 2);
            float wA = (ix0 == base)     ? wx0 : ((ix1 == base)     ? wx1 : 0.0f);
            float wB = (ix1 == base + 1) ? wx1 : ((ix0 == base + 1) ? wx0 : 0.0f);
            float wr = wrs[p];
            float wy0v = ((iy0 >= 0) && (iy0 < H)) ? wy0 * wr : 0.0f;
            float wy1v = ((iy1 >= 0) && (iy1 < H)) ? wy1 * wr : 0.0f;
            int cy0 = min(max(iy0, 0), H - 1);
            int cy1 = min(max(iy1, 0), H - 1);

            int l0 = base - colbase;
            int r0 = cy0 - rowbase, r1 = cy1 - rowbase;
            bool anyx = (wA != 0.0f) || (wB != 0.0f);
            bool anyy = (wy0v != 0.0f) || (wy1v != 0.0f);
            bool cb  = (l0 < 0 || l0 > TW - 2) && anyx && anyy;
            bool rb0 = (r0 < 0 || r0 > TH - 1) && (wy0v != 0.0f) && anyx;
            bool rb1 = (r1 < 0 || r1 > TH - 1) && (wy1v != 0.0f) && anyx;
            flag |= (int)(cb || rb0 || rb1);
            l0 = min(max(l0, 0), TW - 2);
            r0 = min(max(r0, 0), TH - 1);
            r1 = min(max(r1, 0), TH - 1);

            offL0[r][p] = r0 * TW + l0;
            offL1[r][p] = r1 * TW + l0;
            offG0[r][p] = cy0 * W + base;
            offG1[r][p] = cy1 * W + base;
            wq[r][p][0] = wy0v * wA;
            wq[r][p][1] = wy0v * wB;
            wq[r][p][2] = wy1v * wA;
            wq[r][p][3] = wy1v * wB;
        }
    }

    // Block-uniform fallback: if ANY tap escaped the halo (|mv/4| > ~10 px,
    // ~5 sigma), the whole block uses global gathers instead of LDS.
    int fbB = __syncthreads_or(flag);
    #pragma unroll
    for (int r = 0; r < R; ++r)
        #pragma unroll
        for (int p = 0; p < 4; ++p) {
            off0[r][p] = fbB ? offG0[r][p] : offL0[r][p];
            off1[r][p] = fbB ? offG1[r][p] : offL1[r][p];
        }

    float* ob = out + (size_t)b * C * HW + (size_t)y * W + xb;

    for (int c = cbeg; c < cend; ++c) {
        if (c > cbeg) {
            __syncthreads();             // previous channel's LDS reads done
            if (!fbB) {
                const float* s0 = st0 + (size_t)c * HW;
                const float* s1 = st1 + (size_t)c * HW;
                #pragma unroll
                for (int i = 0; i < 4; ++i) {
                    int idx = t + i * 256;
                    if (idx < TILE_V4) {
                        int row = idx / 22;
                        int off = idx * 4 + row * (W - TW);
                        GLD_LDS16(s0 + off, &tile0[idx * 4]);
                        GLD_LDS16(s1 + off, &tile1[idx * 4]);
                    }
                }
            }
        }
        __syncthreads();                 // staged data visible to all waves

        float res[4];
        if (!fbB) {
            #pragma unroll
            for (int p = 0; p < 4; ++p) {
                float a00 = tile0[off0[0][p]], a01 = tile0[off0[0][p] + 1];
                float a10 = tile0[off1[0][p]], a11 = tile0[off1[0][p] + 1];
                float b00 = tile1[off0[1][p]], b01 = tile1[off0[1][p] + 1];
                float b10 = tile1[off1[1][p]], b11 = tile1[off1[1][p] + 1];
                res[p] = wq[0][p][0] * a00 + wq[0][p][1] * a01
                       + wq[0][p][2] * a10 + wq[0][p][3] * a11
                       + wq[1][p][0] * b00 + wq[1][p][1] * b01
                       + wq[1][p][2] * b10 + wq[1][p][3] * b11;
            }
        } else {
            const float* pc0 = pl0 + (size_t)c * HW;
            const float* pc1 = pl1 + (size_t)c * HW;
            #pragma unroll
            for (int p = 0; p < 4; ++p) {
                float a00 = pc0[off0[0][p]], a01 = pc0[off0[0][p] + 1];
                float a10 = pc0[off1[0][p]], a11 = pc0[off1[0][p] + 1];
                float b00 = pc1[off0[1][p]], b01 = pc1[off0[1][p] + 1];
                float b10 = pc1[off1[1][p]], b11 = pc1[off1[1][p] + 1];
                res[p] = wq[0][p][0] * a00 + wq[0][p][1] * a01
                       + wq[0][p][2] * a10 + wq[0][p][3] * a11
                       + wq[1][p][0] * b00 + wq[1][p][1] * b01
                       + wq[1][p][2] * b10 + wq[1][p][3] * b11;
            }
        }
        float* oc = ob + (size_t)c * HW;
        #pragma unroll
        for (int p = 0; p < 4; ++p)      // imm-offset scalar stores, 64B-coalesced
            oc[16 * p] = res[p];
    }
}

extern "C" void kernel_launch(void* const* d_in, const int* in_sizes, int n_in,
                              void* d_out, int out_size, void* d_ws, size_t ws_size,
                              hipStream_t stream) {
    const float* pred = (const float*)d_in[0];   // [B,R,C,H,W] fp32
    const float* mv   = (const float*)d_in[1];   // [B,R,2,H,W] fp32
    const float* wgt  = (const float*)d_in[2];   // [B,R,1,H,W] fp32
    float* out = (float*)d_out;                  // [B,C,H,W] fp32

    dim3 grid(NSPAT, NCHUNK);            // 512 spatial tiles x 4 channel chunks
    mc_warp_kernel<<<grid, dim3(256), 0, stream>>>(pred, mv, wgt, out);
}

// Round 4
// 150.898 us; speedup vs baseline: 1.6232x; 1.6232x over previous
//
#include <hip/hip_runtime.h>

// Problem constants (from reference): B,R,C,H,W = 4,2,19,256,512
constexpr int B = 4, R = 2, C = 19, H = 256, W = 512;
constexpr int HW = H * W;

// Output tile per block: 64 x 16 px; 256 threads, each thread = 4 consecutive x.
// (R2 tried a strided-px remap to fix LDS banking: conflicts barely moved
// 5.9M->4.7M and the launch_bounds(256,6) register cap spilled the tap state
// to scratch -> 182 MB WRITE_SIZE, 3x slower. Reverted both.)
constexpr int BX = 64, BY = 16;
constexpr int NBX = W / BX;              // 8
constexpr int NBY = H / BY;              // 16
constexpr int NSPAT = B * NBX * NBY;     // 512 spatial tiles
constexpr int NCHUNK = 4;                // channel chunks -> 2048 blocks (~2.7
                                         // resident rounds at 3 blocks/CU: stagger)

// Pred tile staged in LDS per (channel, ref), DOUBLE-BUFFERED.
// Halo 10 px (5 sigma of mv/4; ~0.5% of blocks hit the correct global-gather
// fallback). 4 tiles x 13.02 KB = 52.1 KB -> 3 blocks/CU.
constexpr int TW = 88;                   // 64 + 12 left + 12 right slack; 22 float4/row
constexpr int TH = 37;                   // 16 + 10 up + 11 down
constexpr int TILE_N = TW * TH;          // 3256 floats = 13.02 KB
constexpr int TILE_V4 = TILE_N / 4;      // 814 float4s
// TW = 22*4 exactly -> tile rows pack contiguously: phys float index of the
// idx-th float4 is idx*4, i.e. exactly the wave-linear layout global_load_lds
// needs (uniform LDS base + lane*16B, per-lane GLOBAL source address).

// Direct global->LDS DMA, 16B per lane. No VGPR round-trip (cf. R5/R6: register
// staging buffers spilled to scratch and were 2.4x slower).
#define GLD_LDS16(gsrc, ldst)                                                  \
    __builtin_amdgcn_global_load_lds(                                          \
        (const __attribute__((address_space(1))) void*)(gsrc),                 \
        (__attribute__((address_space(3))) void*)(ldst), 16, 0, 0)

// R4 tap-math body (proven: VGPR 64, zero spill with launch_bounds(256,4)).
// DO NOT tighten launch_bounds (R2: cap 85 -> VGPR 40 -> scratch spill of the
// tap state -> 140 MB/side scratch traffic). DO NOT add register prefetch
// buffers (R5/R6: same failure).
//
// SYNC RULE (R3 failure, absmax 6.06): __syncthreads_or does NOT carry the
// vmcnt(0) drain that __syncthreads does. Every buffer handoff between
// global_load_lds and its ds_read consumers MUST cross a plain
// __syncthreads(). The loop-top barrier below is therefore UNCONDITIONAL.
__global__ __launch_bounds__(256, 4) void mc_warp_kernel(
    const float* __restrict__ pred,   // [B,R,C,H,W]
    const float* __restrict__ mv,     // [B,R,2,H,W] quarter-pel
    const float* __restrict__ wgt,    // [B,R,1,H,W]
    float* __restrict__ out)          // [B,C,H,W]
{
    // [buffer][ref][tile]; double-buffered so stage(c+1) streams into one pair
    // while compute(c) reads the other. The compiler's vmcnt(0)-before-barrier
    // then drains loads that were issued a full compute phase earlier.
    __shared__ float tiles[2][2][TILE_N];

    int t = threadIdx.x;
    // XCD band swizzle on the spatial index: each XCD owns a contiguous
    // (b, y-band); all channel-chunks of a tile land on the same XCD
    // (gridDim.x = 512 is a multiple of 8) -> mv/wgt/pred L2 reuse.
    int xcd  = blockIdx.x & 7;
    int slot = blockIdx.x >> 3;
    int vblk = xcd * (NSPAT / 8) + slot;
    int bx   = vblk & (NBX - 1);
    int by   = (vblk >> 3) & (NBY - 1);
    int b    = vblk >> 7;
    int x0 = bx * BX, y0 = by * BY;
    int tx = t & 15, ty = t >> 4;
    int y  = y0 + ty;
    int xb = x0 + tx * 4;                 // first of this thread's 4 px

    // Tile origin, clamped fully inside the image (staging needs no clamps).
    // colbase stays float4-aligned (x0 mult of 64, W-TW = 424 mult of 4).
    int rowbase = min(max(y0 - 10, 0), H - TH);
    int colbase = min(max(x0 - 12, 0), W - TW);

    const float* pl0 = pred + (size_t)(b * R + 0) * C * HW;
    const float* pl1 = pred + (size_t)(b * R + 1) * C * HW;
    const float* st0 = pl0 + (size_t)rowbase * W + colbase;
    const float* st1 = pl1 + (size_t)rowbase * W + colbase;

    int cbeg = (C * blockIdx.y) / NCHUNK;        // {0,4,9,14}
    int cend = (C * (blockIdx.y + 1)) / NCHUNK;  // {4,9,14,19}

    // Issue the FIRST channel's staging now (into buffer 0); it overlaps with
    // the ~300-op tap-setup math below and is drained by the loop-top
    // __syncthreads(). Unconditional: a fallback block simply never reads it.
    {
        const float* s0 = st0 + (size_t)cbeg * HW;
        const float* s1 = st1 + (size_t)cbeg * HW;
        #pragma unroll
        for (int i = 0; i < 4; ++i) {
            int idx = t + i * 256;
            if (idx < TILE_V4) {
                int row = idx / 22;               // 22 float4s per tile row
                int off = idx * 4 + row * (W - TW);   // == row*W + c4
                GLD_LDS16(s0 + off, &tiles[0][0][idx * 4]);
                GLD_LDS16(s1 + off, &tiles[0][1][idx * 4]);
            }
        }
    }

    // Per-(ref, px) tap state: two row-pair offsets + 4 pair weights.
    int   off0[R][4], off1[R][4];
    int   offL0[R][4], offL1[R][4], offG0[R][4], offG1[R][4];
    float wq[R][4][4];
    int flag = 0;

    #pragma unroll
    for (int r = 0; r < R; ++r) {
        const float* mvp = mv + (size_t)((b * R + r) * 2) * HW + (size_t)y * W + xb;
        float4 mx4 = *(const float4*)(mvp);
        float4 my4 = *(const float4*)(mvp + HW);
        float4 wr4 = *(const float4*)(wgt + (size_t)(b * R + r) * HW + (size_t)y * W + xb);
        float mxs[4] = {mx4.x, mx4.y, mx4.z, mx4.w};
        float mys[4] = {my4.x, my4.y, my4.z, my4.w};
        float wrs[4] = {wr4.x, wr4.y, wr4.z, wr4.w};
        #pragma unroll
        for (int p = 0; p < 4; ++p) {
            int x = xb + p;
            float gx = (float)x + mxs[p] * 0.25f;   // quarter-pel -> pixel
            float gy = (float)y + mys[p] * 0.25f;
            float fx0 = floorf(gx), fy0 = floorf(gy);
            float wx1 = gx - fx0, wx0 = 1.0f - wx1;
            float wy1 = gy - fy0, wy0 = 1.0f - wy1;
            int ix0 = (int)fx0, iy0 = (int)fy0;
            int ix1 = ix0 + 1,  iy1 = iy0 + 1;

            // x pair: shift base into [0, W-2], route wx0/wx1 per element.
            int base = min(max(ix0, 0), W - 2);
            float wA = (ix0 == base)     ? wx0 : ((ix1 == base)     ? wx1 : 0.0f);
            float wB = (ix1 == base + 1) ? wx1 : ((ix0 == base + 1) ? wx0 : 0.0f);
            float wr = wrs[p];
            float wy0v = ((iy0 >= 0) && (iy0 < H)) ? wy0 * wr : 0.0f;
            float wy1v = ((iy1 >= 0) && (iy1 < H)) ? wy1 * wr : 0.0f;
            int cy0 = min(max(iy0, 0), H - 1);
            int cy1 = min(max(iy1, 0), H - 1);

            int l0 = base - colbase;
            int r0 = cy0 - rowbase, r1 = cy1 - rowbase;
            bool anyx = (wA != 0.0f) || (wB != 0.0f);
            bool anyy = (wy0v != 0.0f) || (wy1v != 0.0f);
            bool cb  = (l0 < 0 || l0 > TW - 2) && anyx && anyy;
            bool rb0 = (r0 < 0 || r0 > TH - 1) && (wy0v != 0.0f) && anyx;
            bool rb1 = (r1 < 0 || r1 > TH - 1) && (wy1v != 0.0f) && anyx;
            flag |= (int)(cb || rb0 || rb1);
            l0 = min(max(l0, 0), TW - 2);
            r0 = min(max(r0, 0), TH - 1);
            r1 = min(max(r1, 0), TH - 1);

            offL0[r][p] = r0 * TW + l0;
            offL1[r][p] = r1 * TW + l0;
            offG0[r][p] = cy0 * W + base;
            offG1[r][p] = cy1 * W + base;
            wq[r][p][0] = wy0v * wA;
            wq[r][p][1] = wy0v * wB;
            wq[r][p][2] = wy1v * wA;
            wq[r][p][3] = wy1v * wB;
        }
    }

    // Block-uniform fallback: if ANY tap escaped the halo (|mv/4| > ~10 px,
    // ~5 sigma), the whole block uses global gathers instead of LDS.
    // NOTE: used ONLY for the flag reduction — memory ordering comes from the
    // unconditional __syncthreads() at the loop top.
    int fbB = __syncthreads_or(flag);
    #pragma unroll
    for (int r = 0; r < R; ++r)
        #pragma unroll
        for (int p = 0; p < 4; ++p) {
            off0[r][p] = fbB ? offG0[r][p] : offL0[r][p];
            off1[r][p] = fbB ? offG1[r][p] : offL1[r][p];
        }

    float* ob = out + (size_t)b * C * HW + (size_t)y * W + xb;

    int cur = 0;
    for (int c = cbeg; c < cend; ++c, cur ^= 1) {
        // UNCONDITIONAL barrier (see SYNC RULE above): (a) drains stage(c) --
        // issued before compute(c-1), so its HBM latency hid under a full
        // compute phase (prologue staging for c==cbeg, hidden under tap math);
        // (b) guarantees buf[cur^1]'s readers are done before we overwrite it.
        __syncthreads();

        // Issue next channel's staging into the OTHER buffer, then compute.
        if (!fbB && c + 1 < cend) {
            const float* s0 = st0 + (size_t)(c + 1) * HW;
            const float* s1 = st1 + (size_t)(c + 1) * HW;
            #pragma unroll
            for (int i = 0; i < 4; ++i) {
                int idx = t + i * 256;
                if (idx < TILE_V4) {
                    int row = idx / 22;
                    int off = idx * 4 + row * (W - TW);
                    GLD_LDS16(s0 + off, &tiles[cur ^ 1][0][idx * 4]);
                    GLD_LDS16(s1 + off, &tiles[cur ^ 1][1][idx * 4]);
                }
            }
        }

        float res[4];
        if (!fbB) {
            const float* tb0 = &tiles[cur][0][0];
            const float* tb1 = &tiles[cur][1][0];
            #pragma unroll
            for (int p = 0; p < 4; ++p) {
                float a00 = tb0[off0[0][p]], a01 = tb0[off0[0][p] + 1];
                float a10 = tb0[off1[0][p]], a11 = tb0[off1[0][p] + 1];
                float b00 = tb1[off0[1][p]], b01 = tb1[off0[1][p] + 1];
                float b10 = tb1[off1[1][p]], b11 = tb1[off1[1][p] + 1];
                res[p] = wq[0][p][0] * a00 + wq[0][p][1] * a01
                       + wq[0][p][2] * a10 + wq[0][p][3] * a11
                       + wq[1][p][0] * b00 + wq[1][p][1] * b01
                       + wq[1][p][2] * b10 + wq[1][p][3] * b11;
            }
        } else {
            const float* pc0 = pl0 + (size_t)c * HW;
            const float* pc1 = pl1 + (size_t)c * HW;
            #pragma unroll
            for (int p = 0; p < 4; ++p) {
                float a00 = pc0[off0[0][p]], a01 = pc0[off0[0][p] + 1];
                float a10 = pc0[off1[0][p]], a11 = pc0[off1[0][p] + 1];
                float b00 = pc1[off0[1][p]], b01 = pc1[off0[1][p] + 1];
                float b10 = pc1[off1[1][p]], b11 = pc1[off1[1][p] + 1];
                res[p] = wq[0][p][0] * a00 + wq[0][p][1] * a01
                       + wq[0][p][2] * a10 + wq[0][p][3] * a11
                       + wq[1][p][0] * b00 + wq[1][p][1] * b01
                       + wq[1][p][2] * b10 + wq[1][p][3] * b11;
            }
        }
        *(float4*)(ob + (size_t)c * HW) = make_float4(res[0], res[1], res[2], res[3]);
    }
}

extern "C" void kernel_launch(void* const* d_in, const int* in_sizes, int n_in,
                              void* d_out, int out_size, void* d_ws, size_t ws_size,
                              hipStream_t stream) {
    const float* pred = (const float*)d_in[0];   // [B,R,C,H,W] fp32
    const float* mv   = (const float*)d_in[1];   // [B,R,2,H,W] fp32
    const float* wgt  = (const float*)d_in[2];   // [B,R,1,H,W] fp32
    float* out = (float*)d_out;                  // [B,C,H,W] fp32

    dim3 grid(NSPAT, NCHUNK);            // 512 spatial tiles x 4 channel chunks
    mc_warp_kernel<<<grid, dim3(256), 0, stream>>>(pred, mv, wgt, out);
}